// Round 1
// baseline (647.948 us; speedup 1.0000x reference)
//
#include <hip/hip_runtime.h>
#include <math.h>

#define NI 2048
#define NJ 32
#define ND 128
#define NV 32
#define NB 64

typedef _Float16 f16x8 __attribute__((ext_vector_type(8)));
typedef float f32x4 __attribute__((ext_vector_type(4)));

__device__ __forceinline__ unsigned short f2h(float f) {
  _Float16 h = (_Float16)f;
  return __builtin_bit_cast(unsigned short, h);
}
__device__ __forceinline__ float h2f(unsigned short u) {
  return (float)__builtin_bit_cast(_Float16, u);
}

// ---------------------------------------------------------------------------
// K1: u_hat[i][j][b][v] (fp16) = sum_d x[b,i,d] * W[i,j,d,v]
// One block per i. 4 waves, each wave handles 8 j's. MFMA 16x16x32 f16.
// ---------------------------------------------------------------------------
__global__ __launch_bounds__(256, 3) void k_uhat(
    const float* __restrict__ x, const float* __restrict__ W,
    unsigned short* __restrict__ uhat) {
  const int i = blockIdx.x;
  const int tid = threadIdx.x;
  const int wave = tid >> 6;
  const int lane = tid & 63;
  __shared__ unsigned short xs[64][136];  // fp16 x_i tile, padded stride

  // Stage x[:, i, :] -> LDS fp16. thread t: row b = t>>2, d0 = (t&3)*32
  {
    const int b = tid >> 2;
    const int d0 = (tid & 3) * 32;
    const float* xp = x + ((size_t)b * NI + i) * ND + d0;
#pragma unroll
    for (int c2 = 0; c2 < 8; ++c2) {
      f32x4 v = *(const f32x4*)(xp + 4 * c2);
      ushort4 h;
      h.x = f2h(v.x); h.y = f2h(v.y); h.z = f2h(v.z); h.w = f2h(v.w);
      *(ushort4*)&xs[b][d0 + 4 * c2] = h;
    }
  }
  __syncthreads();

  const int li = lane & 15;
  const int lg = lane >> 4;

  // A fragments: A[m=b][k=d]; lane holds m = lane&15, k = 8*(lane>>4)+e
  f16x8 afrag[4][4];
#pragma unroll
  for (int m = 0; m < 4; ++m)
#pragma unroll
    for (int ks = 0; ks < 4; ++ks)
      afrag[m][ks] = *(const f16x8*)&xs[m * 16 + li][ks * 32 + lg * 8];

#pragma unroll 1
  for (int jj = 0; jj < 8; ++jj) {
    const int j = wave * 8 + jj;
    const float* wp = W + ((size_t)i * NJ + j) * (ND * NV);  // [d][v]
    f32x4 acc[4][2];
#pragma unroll
    for (int m = 0; m < 4; ++m)
#pragma unroll
      for (int n = 0; n < 2; ++n)
        acc[m][n] = (f32x4){0.f, 0.f, 0.f, 0.f};

#pragma unroll
    for (int ks = 0; ks < 4; ++ks) {
      f16x8 bfrag[2];
#pragma unroll
      for (int n = 0; n < 2; ++n) {
        // B[k=d][n=v]; lane holds n = lane&15, k = 8*(lane>>4)+e
        const float* bp = wp + (size_t)(ks * 32 + lg * 8) * NV + n * 16 + li;
        f16x8 bf;
#pragma unroll
        for (int e = 0; e < 8; ++e) bf[e] = (_Float16)bp[(size_t)e * NV];
        bfrag[n] = bf;
      }
#pragma unroll
      for (int m = 0; m < 4; ++m)
#pragma unroll
        for (int n = 0; n < 2; ++n)
          acc[m][n] = __builtin_amdgcn_mfma_f32_16x16x32_f16(
              afrag[m][ks], bfrag[n], acc[m][n], 0, 0, 0);
    }

    // C layout: col(v) = lane&15, row(b) = 4*(lane>>4) + reg  [m89-verified]
    unsigned short* up = uhat + ((size_t)i * NJ + j) * (NB * NV);
#pragma unroll
    for (int m = 0; m < 4; ++m)
#pragma unroll
      for (int n = 0; n < 2; ++n) {
        const int v0 = n * 16 + li;
        const int b0 = m * 16 + lg * 4;
#pragma unroll
        for (int r = 0; r < 4; ++r)
          up[(size_t)(b0 + r) * NV + v0] = f2h(acc[m][n][r]);
      }
  }
}

// ---------------------------------------------------------------------------
// zero the routing-logit buffer (must happen every call; ws is not re-poisoned)
// ---------------------------------------------------------------------------
__global__ void k_zero(float* __restrict__ p, int n) {
  const int idx = blockIdx.x * 256 + threadIdx.x;
  if (idx < n) p[idx] = 0.0f;
}

// ---------------------------------------------------------------------------
// softmax over i for each j. b,c stored [j][i]. One block per j.
// ---------------------------------------------------------------------------
__global__ __launch_bounds__(256) void k_softmax(
    const float* __restrict__ b, float* __restrict__ c) {
  const int j = blockIdx.x;
  const int tid = threadIdx.x;
  const int wave = tid >> 6;
  const int lane = tid & 63;
  __shared__ float red[4];
  const float* bj = b + (size_t)j * NI;
  float vals[8];
  float mx = -3.0e38f;
#pragma unroll
  for (int k = 0; k < 8; ++k) {
    vals[k] = bj[tid + 256 * k];
    mx = fmaxf(mx, vals[k]);
  }
#pragma unroll
  for (int off = 32; off > 0; off >>= 1) mx = fmaxf(mx, __shfl_xor(mx, off));
  if (lane == 0) red[wave] = mx;
  __syncthreads();
  mx = fmaxf(fmaxf(red[0], red[1]), fmaxf(red[2], red[3]));
  __syncthreads();
  float sum = 0.0f;
#pragma unroll
  for (int k = 0; k < 8; ++k) {
    vals[k] = expf(vals[k] - mx);
    sum += vals[k];
  }
#pragma unroll
  for (int off = 32; off > 0; off >>= 1) sum += __shfl_xor(sum, off);
  if (lane == 0) red[wave] = sum;
  __syncthreads();
  sum = red[0] + red[1] + red[2] + red[3];
  const float inv = 1.0f / sum;
  float* cj = c + (size_t)j * NI;
#pragma unroll
  for (int k = 0; k < 8; ++k) cj[tid + 256 * k] = vals[k] * inv;
}

// ---------------------------------------------------------------------------
// s partials: spart[ch][b][j][v] = sum_{i in chunk ch} c[j][i]*u_hat[i][j][b][v]
// grid = 32 chunks * 32 j. Deterministic (no atomics).
// ---------------------------------------------------------------------------
__global__ __launch_bounds__(256) void k_s(
    const unsigned short* __restrict__ uhat, const float* __restrict__ c,
    float* __restrict__ spart) {
  const int j = blockIdx.x & 31;
  const int ch = blockIdx.x >> 5;
  const int tid = threadIdx.x;
  const int f0 = tid * 8;  // 8 consecutive (b,v) slots
  float acc[8] = {0, 0, 0, 0, 0, 0, 0, 0};
  const float* cj = c + (size_t)j * NI;
  const int i0 = ch * 64;
#pragma unroll 4
  for (int ii = 0; ii < 64; ++ii) {
    const int i = i0 + ii;
    const float cw = cj[i];
    const uint4 q = *(const uint4*)(uhat + ((size_t)(i * NJ + j)) * (NB * NV) + f0);
    acc[0] = fmaf(cw, h2f((unsigned short)(q.x & 0xffff)), acc[0]);
    acc[1] = fmaf(cw, h2f((unsigned short)(q.x >> 16)), acc[1]);
    acc[2] = fmaf(cw, h2f((unsigned short)(q.y & 0xffff)), acc[2]);
    acc[3] = fmaf(cw, h2f((unsigned short)(q.y >> 16)), acc[3]);
    acc[4] = fmaf(cw, h2f((unsigned short)(q.z & 0xffff)), acc[4]);
    acc[5] = fmaf(cw, h2f((unsigned short)(q.z >> 16)), acc[5]);
    acc[6] = fmaf(cw, h2f((unsigned short)(q.w & 0xffff)), acc[6]);
    acc[7] = fmaf(cw, h2f((unsigned short)(q.w >> 16)), acc[7]);
  }
  const int b = f0 >> 5;
  const int v0 = f0 & 31;
  float* sp = spart + (size_t)ch * (NB * NJ * NV) + (size_t)b * (NJ * NV) + j * NV + v0;
  *(f32x4*)sp = (f32x4){acc[0], acc[1], acc[2], acc[3]};
  *(f32x4*)(sp + 4) = (f32x4){acc[4], acc[5], acc[6], acc[7]};
}

// ---------------------------------------------------------------------------
// squash: reduce 32 chunk-partials -> s[b][j][v]; mag_sq over j per (b,v);
// vout[b][j][v] = mag_sq/(1+mag_sq) * s / sqrt(mag_sq + 1e-9)
// grid = 64 (one block per b), 1024 threads (j = tid>>5, v = tid&31).
// ---------------------------------------------------------------------------
__global__ __launch_bounds__(1024) void k_squash(
    const float* __restrict__ spart, float* __restrict__ vout) {
  const int b = blockIdx.x;
  const int tid = threadIdx.x;
  const int j = tid >> 5;
  const int v = tid & 31;
  float s = 0.0f;
#pragma unroll 8
  for (int ch = 0; ch < 32; ++ch)
    s += spart[(size_t)ch * (NB * NJ * NV) + (size_t)b * (NJ * NV) + tid];
  __shared__ float sq[NJ][NV + 1];
  sq[j][v] = s * s;
  __syncthreads();
#pragma unroll
  for (int off = 16; off > 0; off >>= 1) {
    if (j < off) sq[j][v] += sq[j + off][v];
    __syncthreads();
  }
  const float msq = sq[0][v];
  const float f = msq / ((1.0f + msq) * sqrtf(msq + 1e-9f));
  vout[(size_t)b * (NJ * NV) + tid] = f * s;
}

// ---------------------------------------------------------------------------
// agreement: b[j][i] += (1/64) * sum_{b,v} u_hat[i][j][b][v] * vt[b][j][v]
// one wave per (i,j) pair; lane = batch index.
// ---------------------------------------------------------------------------
__global__ __launch_bounds__(256) void k_agree(
    const unsigned short* __restrict__ uhat, const float* __restrict__ vt,
    float* __restrict__ bacc) {
  const int p = blockIdx.x * 4 + (threadIdx.x >> 6);  // p = i*32 + j
  const int lane = threadIdx.x & 63;
  const int j = p & 31;
  const unsigned short* up = uhat + (size_t)p * (NB * NV) + lane * NV;
  const float* vp = vt + (size_t)lane * (NJ * NV) + j * NV;
  float dot = 0.0f;
#pragma unroll
  for (int q = 0; q < 8; ++q) {
    const uint2 u2 = *(const uint2*)(up + q * 4);
    const f32x4 w = *(const f32x4*)(vp + q * 4);
    dot += h2f((unsigned short)(u2.x & 0xffff)) * w.x;
    dot += h2f((unsigned short)(u2.x >> 16)) * w.y;
    dot += h2f((unsigned short)(u2.y & 0xffff)) * w.z;
    dot += h2f((unsigned short)(u2.y >> 16)) * w.w;
  }
#pragma unroll
  for (int off = 32; off > 0; off >>= 1) dot += __shfl_xor(dot, off);
  if (lane == 0) {
    const int i = p >> 5;
    bacc[(size_t)j * NI + i] += dot * (1.0f / 64.0f);
  }
}

// ---------------------------------------------------------------------------
extern "C" void kernel_launch(void* const* d_in, const int* in_sizes, int n_in,
                              void* d_out, int out_size, void* d_ws, size_t ws_size,
                              hipStream_t stream) {
  (void)in_sizes; (void)n_in; (void)out_size; (void)ws_size;
  const float* x = (const float*)d_in[0];
  const float* W = (const float*)d_in[1];
  float* out = (float*)d_out;

  char* ws = (char*)d_ws;
  const size_t UHAT_BYTES = (size_t)NI * NJ * NB * NV * 2;  // 268,435,456
  unsigned short* uhat = (unsigned short*)ws;
  float* bbuf = (float*)(ws + UHAT_BYTES);         // [NJ][NI]
  float* cbuf = bbuf + (size_t)NI * NJ;            // [NJ][NI]
  float* spart = cbuf + (size_t)NI * NJ;           // [32][NB][NJ][NV]
  float* vt = spart + (size_t)32 * NB * NJ * NV;   // [NB][NJ][NV]

  k_zero<<<dim3((NI * NJ + 255) / 256), dim3(256), 0, stream>>>(bbuf, NI * NJ);
  k_uhat<<<dim3(NI), dim3(256), 0, stream>>>(x, W, uhat);

  for (int it = 0; it < 3; ++it) {
    k_softmax<<<dim3(NJ), dim3(256), 0, stream>>>(bbuf, cbuf);
    k_s<<<dim3(1024), dim3(256), 0, stream>>>(uhat, cbuf, spart);
    k_squash<<<dim3(NB), dim3(1024), 0, stream>>>(spart, it == 2 ? out : vt);
    if (it < 2)
      k_agree<<<dim3(NI * NJ / 4), dim3(256), 0, stream>>>(uhat, vt, bbuf);
  }
}

// Round 2
// 506.841 us; speedup vs baseline: 1.2784x; 1.2784x over previous
//
#include <hip/hip_runtime.h>
#include <math.h>

#define NI 2048
#define NJ 32
#define ND 128
#define NV 32
#define NB 64

typedef _Float16 f16x8 __attribute__((ext_vector_type(8)));
typedef float f32x4 __attribute__((ext_vector_type(4)));

__device__ __forceinline__ unsigned short f2h(float f) {
  _Float16 h = (_Float16)f;
  return __builtin_bit_cast(unsigned short, h);
}
__device__ __forceinline__ float h2f(unsigned short u) {
  return (float)__builtin_bit_cast(_Float16, u);
}

// ---------------------------------------------------------------------------
// K1: u_hat[i][j][b][v] (fp16) = sum_d x[b,i,d] * W[i,j,d,v]
// One block per i. 4 waves x 8 j each. MFMA 16x16x32 f16.
// W loads software-pipelined 1 ks-step (16 f32/lane) ahead.
// ---------------------------------------------------------------------------
#define LOADKS(dst, wp, ks)                                                    \
  {                                                                            \
    _Pragma("unroll") for (int n = 0; n < 2; ++n) {                            \
      const float* bp =                                                        \
          (wp) + (size_t)((ks) * 32 + lg * 8) * NV + n * 16 + li;              \
      _Pragma("unroll") for (int e = 0; e < 8; ++e)                            \
          dst[n * 8 + e] = bp[(size_t)e * NV];                                 \
    }                                                                          \
  }

__global__ __launch_bounds__(256, 2) void k_uhat(
    const float* __restrict__ x, const float* __restrict__ W,
    unsigned short* __restrict__ uhat) {
  const int i = blockIdx.x;
  const int tid = threadIdx.x;
  const int wave = tid >> 6;
  const int lane = tid & 63;
  __shared__ unsigned short xs[64][136];  // fp16 x_i tile, padded stride

  // Stage x[:, i, :] -> LDS fp16. thread t: row b = t>>2, d0 = (t&3)*32
  {
    const int b = tid >> 2;
    const int d0 = (tid & 3) * 32;
    const float* xp = x + ((size_t)b * NI + i) * ND + d0;
#pragma unroll
    for (int c2 = 0; c2 < 8; ++c2) {
      f32x4 v = *(const f32x4*)(xp + 4 * c2);
      ushort4 h;
      h.x = f2h(v.x); h.y = f2h(v.y); h.z = f2h(v.z); h.w = f2h(v.w);
      *(ushort4*)&xs[b][d0 + 4 * c2] = h;
    }
  }
  __syncthreads();

  const int li = lane & 15;
  const int lg = lane >> 4;

  // A fragments: A[m=b][k=d]; lane holds m = lane&15, k = 8*(lane>>4)+e
  f16x8 afrag[4][4];
#pragma unroll
  for (int m = 0; m < 4; ++m)
#pragma unroll
    for (int ks = 0; ks < 4; ++ks)
      afrag[m][ks] = *(const f16x8*)&xs[m * 16 + li][ks * 32 + lg * 8];

  const float* wp0 = W + ((size_t)i * NJ + wave * 8) * (ND * NV);
  float raw[2][16];
  LOADKS(raw[0], wp0, 0)

#pragma unroll 1
  for (int jj = 0; jj < 8; ++jj) {
    const int j = wave * 8 + jj;
    const float* wp = wp0 + (size_t)jj * (ND * NV);
    f32x4 acc[4][2];
#pragma unroll
    for (int m = 0; m < 4; ++m)
#pragma unroll
      for (int n = 0; n < 2; ++n)
        acc[m][n] = (f32x4){0.f, 0.f, 0.f, 0.f};

#pragma unroll
    for (int ks = 0; ks < 4; ++ks) {
      const int cur = ks & 1;
      const int nxt = cur ^ 1;
      // prefetch next ks step (wraps to next j; last wraps harmlessly to j0)
      if (ks < 3) {
        LOADKS(raw[nxt], wp, ks + 1)
      } else {
        const int jn = (jj + 1) & 7;
        const float* wpn = wp0 + (size_t)jn * (ND * NV);
        LOADKS(raw[nxt], wpn, 0)
      }
      f16x8 bfrag[2];
#pragma unroll
      for (int n = 0; n < 2; ++n) {
        f16x8 bf;
#pragma unroll
        for (int e = 0; e < 8; ++e) bf[e] = (_Float16)raw[cur][n * 8 + e];
        bfrag[n] = bf;
      }
#pragma unroll
      for (int m = 0; m < 4; ++m)
#pragma unroll
        for (int n = 0; n < 2; ++n)
          acc[m][n] = __builtin_amdgcn_mfma_f32_16x16x32_f16(
              afrag[m][ks], bfrag[n], acc[m][n], 0, 0, 0);
    }

    // C layout: col(v) = lane&15, row(b) = 4*(lane>>4) + reg  [m89-verified]
    unsigned short* up = uhat + ((size_t)i * NJ + j) * (NB * NV);
#pragma unroll
    for (int m = 0; m < 4; ++m)
#pragma unroll
      for (int n = 0; n < 2; ++n) {
        const int v0 = n * 16 + li;
        const int b0 = m * 16 + lg * 4;
#pragma unroll
        for (int r = 0; r < 4; ++r)
          up[(size_t)(b0 + r) * NV + v0] = f2h(acc[m][n][r]);
      }
  }
}

// ---------------------------------------------------------------------------
// pass0: spart[ch][b][j][v] = sum_{i in chunk} u_hat[i][j][b][v]
// (c0 is uniform 1/2048; the scale is applied in squash)
// ---------------------------------------------------------------------------
__global__ __launch_bounds__(256) void k_pass0(
    const unsigned short* __restrict__ uhat, float* __restrict__ spart) {
  const int j = blockIdx.x & 31;
  const int ch = blockIdx.x >> 5;
  const int tid = threadIdx.x;
  const int f0 = tid * 8;
  float acc[8] = {0, 0, 0, 0, 0, 0, 0, 0};
  const int i0 = ch * 64;
#pragma unroll 4
  for (int ii = 0; ii < 64; ++ii) {
    const int i = i0 + ii;
    const uint4 q = *(const uint4*)(uhat + ((size_t)(i * NJ + j)) * (NB * NV) + f0);
    acc[0] += h2f((unsigned short)(q.x & 0xffff));
    acc[1] += h2f((unsigned short)(q.x >> 16));
    acc[2] += h2f((unsigned short)(q.y & 0xffff));
    acc[3] += h2f((unsigned short)(q.y >> 16));
    acc[4] += h2f((unsigned short)(q.z & 0xffff));
    acc[5] += h2f((unsigned short)(q.z >> 16));
    acc[6] += h2f((unsigned short)(q.w & 0xffff));
    acc[7] += h2f((unsigned short)(q.w >> 16));
  }
  const int b = f0 >> 5;
  const int v0 = f0 & 31;
  float* sp = spart + (size_t)ch * (NB * NJ * NV) + (size_t)b * (NJ * NV) + j * NV + v0;
  *(f32x4*)sp = (f32x4){acc[0], acc[1], acc[2], acc[3]};
  *(f32x4*)(sp + 4) = (f32x4){acc[4], acc[5], acc[6], acc[7]};
}

// ---------------------------------------------------------------------------
// fused routing pass (iterations 1,2): per (chunk, j) block, for each i:
//   agree = sum_{b,v} uhat[i,j,b,v] * vprev[b,j,v]   (block reduce)
//   bnew  = bprev + agree/64 ; w = exp(bnew)  (unnormalized softmax weight)
//   stilde += w * uhat[i,j]  ;  Zpart += w
// ---------------------------------------------------------------------------
__global__ __launch_bounds__(256) void k_route(
    const unsigned short* __restrict__ uhat, const float* __restrict__ vprev,
    const float* __restrict__ bin, float* __restrict__ bout,
    float* __restrict__ spart, float* __restrict__ Zpart) {
  const int j = blockIdx.x & 31;
  const int ch = blockIdx.x >> 5;
  const int tid = threadIdx.x;
  const int wave = tid >> 6;
  const int lane = tid & 63;
  const int f0 = tid * 8;
  const int b = f0 >> 5;
  const int v0 = f0 & 31;
  __shared__ float red[2][4];

  // v_prev values for this thread's 8 (b,v) slots are i-invariant: hoist.
  const float* vp = vprev + (size_t)b * (NJ * NV) + j * NV + v0;
  const f32x4 vva = *(const f32x4*)vp;
  const f32x4 vvb = *(const f32x4*)(vp + 4);

  float acc[8] = {0, 0, 0, 0, 0, 0, 0, 0};
  float zacc = 0.0f;
  const int i0 = ch * 64;
#pragma unroll 2
  for (int ii = 0; ii < 64; ++ii) {
    const int i = i0 + ii;
    // read b BEFORE the barrier so the in-place write below can't race it
    const float bprev = bin ? bin[(size_t)j * NI + i] : 0.0f;
    const uint4 q = *(const uint4*)(uhat + ((size_t)(i * NJ + j)) * (NB * NV) + f0);
    float h[8];
    h[0] = h2f((unsigned short)(q.x & 0xffff));
    h[1] = h2f((unsigned short)(q.x >> 16));
    h[2] = h2f((unsigned short)(q.y & 0xffff));
    h[3] = h2f((unsigned short)(q.y >> 16));
    h[4] = h2f((unsigned short)(q.z & 0xffff));
    h[5] = h2f((unsigned short)(q.z >> 16));
    h[6] = h2f((unsigned short)(q.w & 0xffff));
    h[7] = h2f((unsigned short)(q.w >> 16));
    float dp = h[0] * vva.x + h[1] * vva.y + h[2] * vva.z + h[3] * vva.w +
               h[4] * vvb.x + h[5] * vvb.y + h[6] * vvb.z + h[7] * vvb.w;
#pragma unroll
    for (int off = 32; off > 0; off >>= 1) dp += __shfl_xor(dp, off);
    const int par = ii & 1;
    if (lane == 0) red[par][wave] = dp;
    __syncthreads();
    const float agree = red[par][0] + red[par][1] + red[par][2] + red[par][3];
    const float bnew = bprev + agree * (1.0f / 64.0f);
    const float w = expf(bnew);
    if (tid == 0) bout[(size_t)j * NI + i] = bnew;
#pragma unroll
    for (int e = 0; e < 8; ++e) acc[e] = fmaf(w, h[e], acc[e]);
    zacc += w;
  }
  if (tid == 0) Zpart[ch * NJ + j] = zacc;
  float* sp = spart + (size_t)ch * (NB * NJ * NV) + (size_t)b * (NJ * NV) + j * NV + v0;
  *(f32x4*)sp = (f32x4){acc[0], acc[1], acc[2], acc[3]};
  *(f32x4*)(sp + 4) = (f32x4){acc[4], acc[5], acc[6], acc[7]};
}

// ---------------------------------------------------------------------------
// squash: s[b][j][v] = scale_j * sum_ch spart ; msq over j per (b,v);
// vout = msq/(1+msq) * s / sqrt(msq + 1e-9).  scale_j = 1/Z_j or scale0.
// grid = 64 (one block per b), 1024 threads (j = tid>>5, v = tid&31).
// ---------------------------------------------------------------------------
__global__ __launch_bounds__(1024) void k_squash(
    const float* __restrict__ spart, const float* __restrict__ Zpart,
    const float scale0, float* __restrict__ vout) {
  const int b = blockIdx.x;
  const int tid = threadIdx.x;
  const int j = tid >> 5;
  const int v = tid & 31;
  __shared__ float zs[NJ];
  if (Zpart != nullptr) {
    if (tid < NJ) {
      float z = 0.0f;
#pragma unroll
      for (int ch = 0; ch < 32; ++ch) z += Zpart[ch * NJ + tid];
      zs[tid] = 1.0f / z;
    }
    __syncthreads();
  }
  const float scale = (Zpart != nullptr) ? zs[j] : scale0;
  float s = 0.0f;
#pragma unroll 8
  for (int ch = 0; ch < 32; ++ch)
    s += spart[(size_t)ch * (NB * NJ * NV) + (size_t)b * (NJ * NV) + tid];
  s *= scale;
  __shared__ float sq[NJ][NV + 1];
  sq[j][v] = s * s;
  __syncthreads();
#pragma unroll
  for (int off = 16; off > 0; off >>= 1) {
    if (j < off) sq[j][v] += sq[j + off][v];
    __syncthreads();
  }
  const float msq = sq[0][v];
  const float f = msq / ((1.0f + msq) * sqrtf(msq + 1e-9f));
  vout[(size_t)b * (NJ * NV) + tid] = f * s;
}

// ---------------------------------------------------------------------------
extern "C" void kernel_launch(void* const* d_in, const int* in_sizes, int n_in,
                              void* d_out, int out_size, void* d_ws, size_t ws_size,
                              hipStream_t stream) {
  (void)in_sizes; (void)n_in; (void)out_size; (void)ws_size;
  const float* x = (const float*)d_in[0];
  const float* W = (const float*)d_in[1];
  float* out = (float*)d_out;

  char* ws = (char*)d_ws;
  const size_t UHAT_BYTES = (size_t)NI * NJ * NB * NV * 2;  // 268,435,456
  unsigned short* uhat = (unsigned short*)ws;
  float* bbuf = (float*)(ws + UHAT_BYTES);           // [NJ][NI]
  float* spart = bbuf + (size_t)NI * NJ;             // [32][NB][NJ][NV]
  float* vt = spart + (size_t)32 * NB * NJ * NV;     // [NB][NJ][NV]
  float* Zpart = vt + (size_t)NB * NJ * NV;          // [32][NJ]

  k_uhat<<<dim3(NI), dim3(256), 0, stream>>>(x, W, uhat);

  // it0: c uniform -> s0 partials, squash with scale 1/2048
  k_pass0<<<dim3(1024), dim3(256), 0, stream>>>(uhat, spart);
  k_squash<<<dim3(NB), dim3(1024), 0, stream>>>(spart, nullptr, 1.0f / NI, vt);

  // it1: agree0 + unnormalized s1 in one pass (b starts at 0)
  k_route<<<dim3(1024), dim3(256), 0, stream>>>(uhat, vt, nullptr, bbuf, spart, Zpart);
  k_squash<<<dim3(NB), dim3(1024), 0, stream>>>(spart, Zpart, 0.0f, vt);

  // it2: agree1 + unnormalized s2 in one pass
  k_route<<<dim3(1024), dim3(256), 0, stream>>>(uhat, vt, bbuf, bbuf, spart, Zpart);
  k_squash<<<dim3(NB), dim3(1024), 0, stream>>>(spart, Zpart, 0.0f, out);
}